// Round 2
// baseline (1197.318 us; speedup 1.0000x reference)
//
#include <hip/hip_runtime.h>
#include <hip/hip_bf16.h>

typedef short bf16x8 __attribute__((ext_vector_type(8)));
typedef float f32x4  __attribute__((ext_vector_type(4)));

#define N_PTS  1000000
#define K_VOL  27
#define C_IN   64
#define C_OUT  64
#define ROWS_PER_BLOCK 64

static __device__ __forceinline__ short f2bf(float x) {
    __hip_bfloat16 h = __float2bfloat16(x);
    return *(short*)&h;
}

// ---------------------------------------------------------------------------
// Convert features fp32 [N][64] -> bf16 [N][64] in ws. 8 elems per thread.
// ---------------------------------------------------------------------------
__global__ __launch_bounds__(256) void cvt_feat(const float* __restrict__ f,
                                                __hip_bfloat16* __restrict__ o,
                                                int n8) {
    int id = blockIdx.x * 256 + threadIdx.x;
    if (id >= n8) return;
    const float4* src = (const float4*)f;
    float4 a = src[id * 2 + 0];
    float4 b = src[id * 2 + 1];
    bf16x8 v;
    v[0] = f2bf(a.x); v[1] = f2bf(a.y); v[2] = f2bf(a.z); v[3] = f2bf(a.w);
    v[4] = f2bf(b.x); v[5] = f2bf(b.y); v[6] = f2bf(b.z); v[7] = f2bf(b.w);
    ((bf16x8*)o)[id] = v;
}

// ---------------------------------------------------------------------------
// Repack W fp32 [27][64][64] (k, ci, co) -> bf16 MFMA-B-fragment order.
// chunk id = k*512 + s*256 + t*64 + lane  (s = k-step 0/1, t = col-tile 0..3)
// elem j of chunk = W[k][s*32 + (lane>>4)*8 + j][t*16 + (lane&15)]
// ---------------------------------------------------------------------------
__global__ void repack_w(const float* __restrict__ W,
                         __hip_bfloat16* __restrict__ outw) {
    int id = blockIdx.x * 256 + threadIdx.x;          // 0 .. 27*2*4*64-1
    if (id >= K_VOL * 2 * 4 * 64) return;
    int lane = id & 63;
    int t    = (id >> 6) & 3;
    int s    = (id >> 8) & 1;
    int k    = id >> 9;
    int ci0  = s * 32 + (lane >> 4) * 8;
    int co   = t * 16 + (lane & 15);
    const float* src = W + (k * C_IN + ci0) * C_OUT + co;
    bf16x8 v;
#pragma unroll
    for (int j = 0; j < 8; ++j) v[j] = f2bf(src[j * C_OUT]);
    ((bf16x8*)outw)[id] = v;
}

// ---------------------------------------------------------------------------
// Main gather-GEMM. Block = 64 rows x 64 cols. 4 waves; wave handles 16 rows
// with 4x mfma_f32_16x16x32_bf16 accumulators (one per 16-col tile).
// A gathered straight from global bf16 (16B/lane); masked rows contribute 0.
// ---------------------------------------------------------------------------
__global__ __launch_bounds__(256, 4) void sconv_kernel(
    const __hip_bfloat16* __restrict__ feat,
    const int* __restrict__ kmap,
    const int* __restrict__ kmask,
    const __hip_bfloat16* __restrict__ wfrag,
    float* __restrict__ out) {

    __shared__ int s_idx[ROWS_PER_BLOCK * K_VOL];

    const int tid    = threadIdx.x;
    const int rb     = blockIdx.x * ROWS_PER_BLOCK;   // block row base
    const int base27 = rb * K_VOL;                    // kmap/mask are [N][27] row-major

    // Stage pre-masked indices: s_idx[row_local*27 + k] = mask ? kmap : -1
    for (int i = tid; i < ROWS_PER_BLOCK * K_VOL; i += 256) {
        int m    = kmask[base27 + i];
        s_idx[i] = m ? kmap[base27 + i] : -1;
    }
    __syncthreads();

    const int lane = tid & 63;
    const int wave = tid >> 6;
    const int mrow = lane & 15;     // A-operand row within the 16-row tile
    const int g    = lane >> 4;     // k-quad: A k-slice = g*8 .. g*8+7

    const bf16x8* f8 = (const bf16x8*)feat;   // feature row = 8 chunks of 16B
    const bf16x8* w8 = (const bf16x8*)wfrag;

    f32x4 acc0 = {0.f, 0.f, 0.f, 0.f};
    f32x4 acc1 = {0.f, 0.f, 0.f, 0.f};
    f32x4 acc2 = {0.f, 0.f, 0.f, 0.f};
    f32x4 acc3 = {0.f, 0.f, 0.f, 0.f};

    const int* myidx = &s_idx[(wave * 16 + mrow) * K_VOL];

    for (int k = 0; k < K_VOL; ++k) {
        int idx = myidx[k];
        bf16x8 a0 = {0, 0, 0, 0, 0, 0, 0, 0};
        bf16x8 a1 = {0, 0, 0, 0, 0, 0, 0, 0};
        if (idx >= 0) {
            const bf16x8* fr = f8 + (size_t)idx * 8 + g;
            a0 = fr[0];   // ci = g*8 .. g*8+7        (k-step s=0)
            a1 = fr[4];   // ci = 32 + g*8 .. +7      (k-step s=1)
        }
        const bf16x8* wb = w8 + (size_t)k * 512 + lane;
        bf16x8 b00 = wb[0 * 64];          // s=0, t=0
        bf16x8 b01 = wb[1 * 64];          // s=0, t=1
        bf16x8 b02 = wb[2 * 64];          // s=0, t=2
        bf16x8 b03 = wb[3 * 64];          // s=0, t=3
        bf16x8 b10 = wb[256 + 0 * 64];    // s=1, t=0
        bf16x8 b11 = wb[256 + 1 * 64];
        bf16x8 b12 = wb[256 + 2 * 64];
        bf16x8 b13 = wb[256 + 3 * 64];

        acc0 = __builtin_amdgcn_mfma_f32_16x16x32_bf16(a0, b00, acc0, 0, 0, 0);
        acc1 = __builtin_amdgcn_mfma_f32_16x16x32_bf16(a0, b01, acc1, 0, 0, 0);
        acc2 = __builtin_amdgcn_mfma_f32_16x16x32_bf16(a0, b02, acc2, 0, 0, 0);
        acc3 = __builtin_amdgcn_mfma_f32_16x16x32_bf16(a0, b03, acc3, 0, 0, 0);
        acc0 = __builtin_amdgcn_mfma_f32_16x16x32_bf16(a1, b10, acc0, 0, 0, 0);
        acc1 = __builtin_amdgcn_mfma_f32_16x16x32_bf16(a1, b11, acc1, 0, 0, 0);
        acc2 = __builtin_amdgcn_mfma_f32_16x16x32_bf16(a1, b12, acc2, 0, 0, 0);
        acc3 = __builtin_amdgcn_mfma_f32_16x16x32_bf16(a1, b13, acc3, 0, 0, 0);
    }

    // Epilogue. C/D layout (verified m89/m91): col = lane&15, row = (lane>>4)*4 + reg
    const int orow = rb + wave * 16 + g * 4;
    const int ocol = mrow;
#pragma unroll
    for (int j = 0; j < 4; ++j) {
        size_t r = (size_t)(orow + j) * C_OUT;
        out[r +  0 + ocol] = acc0[j];
        out[r + 16 + ocol] = acc1[j];
        out[r + 32 + ocol] = acc2[j];
        out[r + 48 + ocol] = acc3[j];
    }
}

extern "C" void kernel_launch(void* const* d_in, const int* in_sizes, int n_in,
                              void* d_out, int out_size, void* d_ws, size_t ws_size,
                              hipStream_t stream) {
    const float* feat32 = (const float*)d_in[0];   // [1e6][64] fp32
    const float* W      = (const float*)d_in[1];   // [27][64][64] fp32
    const int*   kmap   = (const int*)d_in[2];     // [1e6][27] int32
    const int*   kmask  = (const int*)d_in[3];     // [1e6][27] int32
    float*       out    = (float*)d_out;           // [1e6][64] fp32

    // ws layout: [0, 128MB) bf16 features; then 221184 B repacked bf16 W
    __hip_bfloat16* featbf = (__hip_bfloat16*)d_ws;
    __hip_bfloat16* wfrag  = (__hip_bfloat16*)((char*)d_ws +
                              (size_t)N_PTS * C_IN * sizeof(__hip_bfloat16));

    const int n8 = N_PTS * C_IN / 8;               // 8e6 chunks of 8 elems
    cvt_feat<<<(n8 + 255) / 256, 256, 0, stream>>>(feat32, featbf, n8);

    const int repack_threads = K_VOL * 2 * 4 * 64; // 13824
    repack_w<<<(repack_threads + 255) / 256, 256, 0, stream>>>(W, wfrag);

    const int nblocks = N_PTS / ROWS_PER_BLOCK;    // 15625
    sconv_kernel<<<nblocks, 256, 0, stream>>>(featbf, kmap, kmask, wfrag, out);
}